// Round 4
// baseline (370.032 us; speedup 1.0000x reference)
//
#include <hip/hip_runtime.h>
#include <hip/hip_bf16.h>

#define BATCH 8
#define CHN 256
#define HH 64
#define WW 64
#define HW (HH*WW)
#define DGRP 4
#define CG 64
#define KK 9
#define NGK 36
#define EPSV 1e-5f

typedef __attribute__((ext_vector_type(8))) short short8;
typedef __attribute__((ext_vector_type(4))) float f32x4;

// w_deform (o, g*64+c, kk) fp32 -> w2 bf16 [gk][o][c]; also zero the stats buf.
__global__ __launch_bounds__(256) void wt2_kernel(const float* __restrict__ wd,
                                                  __hip_bfloat16* __restrict__ w2,
                                                  float* __restrict__ st) {
  int idx = blockIdx.x * 256 + threadIdx.x;     // 36*256*64 = 589824
  int c  = idx & 63;
  int o  = (idx >> 6) & 255;
  int gk = idx >> 14;                           // 0..35
  int g = gk / 9, k = gk - g * 9;
  w2[idx] = __float2bfloat16(wd[(o * 256 + g * 64 + c) * 9 + k]);
  if (blockIdx.x < 2) st[blockIdx.x * 256 + threadIdx.x] = 0.f;
}

// One block per (b, h, half-row). 4 waves; wave wv -> o in [wv*64, wv*64+64).
// Software-pipelined: sample tap gk+1 while MFMAing tap gk (double-buffered s_S).
// Fused GroupNorm partial stats via atomics into st[0..255]=sum, st[256..511]=sumsq.
__global__ __launch_bounds__(256) void conv_kernel(
    const float* __restrict__ x, const float* __restrict__ shp,
    const float* __restrict__ woff, const __hip_bfloat16* __restrict__ w2,
    float* __restrict__ out, float* __restrict__ st) {
  __shared__ float s_woff[288];
  __shared__ __align__(16) unsigned short s_S[2][32 * 72];  // [buf][px][c], stride 72

  // XCD swizzle: consecutive blockIdx -> XCDs round-robin; keep b on one XCD.
  const int b    = blockIdx.x & 7;
  const int rem  = blockIdx.x >> 3;          // 0..127
  const int h    = rem >> 1;
  const int px0  = (rem & 1) << 5;           // 0 or 32
  const int t    = threadIdx.x;
  const int wv   = t >> 6;
  const int lane = t & 63;
  const int quad = lane >> 4;
  const int l15  = lane & 15;
  const int spx  = t & 31;                   // sample pixel within half-row
  const int scs  = (t >> 5) << 3;            // sample channel slice (8 ch)
  const int pxg  = px0 + spx;                // global pixel column

  for (int i = t; i < 288; i += 256) s_woff[i] = woff[i];

  const float a0 = shp[((b * 4 + 0) * HH + h) * WW + pxg];
  const float a1 = shp[((b * 4 + 1) * HH + h) * WW + pxg];
  const float a2 = shp[((b * 4 + 2) * HH + h) * WW + pxg];
  const float a3 = shp[((b * 4 + 3) * HH + h) * WW + pxg];

  f32x4 acc[4][2];
#pragma unroll
  for (int mo = 0; mo < 4; ++mo)
#pragma unroll
    for (int np = 0; np < 2; ++np) acc[mo][np] = (f32x4){0.f, 0.f, 0.f, 0.f};

  __syncthreads();   // s_woff ready

  const unsigned short* w2u = (const unsigned short*)w2;

  // ---- sample-descriptor + gather-issue for tap (gk) with kernel dy,dx = (kdy,kdx), group g
  float v00[8], v01[8], v10[8], v11[8];
  float w00, w01, w10, w11;

  auto sample_issue = [&](int gk, int g, int kdy, int kdx) {
    const float* wy = &s_woff[gk * 8];
    float dy = wy[0] * a0 + wy[1] * a1 + wy[2] * a2 + wy[3] * a3;
    float dx = wy[4] * a0 + wy[5] * a1 + wy[6] * a2 + wy[7] * a3;
    float py  = dy + (float)(h + kdy);
    float pxp = dx + (float)(pxg + kdx);
    float y0f = floorf(py), x0f = floorf(pxp);
    float ly = py - y0f, lx = pxp - x0f;
    int y0 = (int)y0f, x0 = (int)x0f;
    float m_y0 = (y0 >=  0 && y0 <= 63) ? 1.f : 0.f;
    float m_y1 = (y0 >= -1 && y0 <= 62) ? 1.f : 0.f;
    float m_x0 = (x0 >=  0 && x0 <= 63) ? 1.f : 0.f;
    float m_x1 = (x0 >= -1 && x0 <= 62) ? 1.f : 0.f;
    w00 = (1.f - ly) * (1.f - lx) * m_y0 * m_x0;
    w01 = (1.f - ly) * lx         * m_y0 * m_x1;
    w10 = ly         * (1.f - lx) * m_y1 * m_x0;
    w11 = ly         * lx         * m_y1 * m_x1;
    int yc0 = min(max(y0, 0), 63),     yc1 = min(max(y0 + 1, 0), 63);
    int xc0 = min(max(x0, 0), 63),     xc1 = min(max(x0 + 1, 0), 63);
    int i00 = (yc0 << 6) + xc0, i01 = (yc0 << 6) + xc1;
    int i10 = (yc1 << 6) + xc0, i11 = (yc1 << 6) + xc1;
    const float* xp = x + (((size_t)(b * DGRP + g) * CG + scs) << 12);
#pragma unroll
    for (int j = 0; j < 8; ++j) {
      const float* xc = xp + ((size_t)j << 12);
      v00[j] = xc[i00]; v01[j] = xc[i01]; v10[j] = xc[i10]; v11[j] = xc[i11];
    }
  };

  auto combine_write = [&](int buf) {
#pragma unroll
    for (int jj = 0; jj < 4; ++jj) {
      float e0 = v00[2*jj]   * w00 + v01[2*jj]   * w01 + v10[2*jj]   * w10 + v11[2*jj]   * w11;
      float e1 = v00[2*jj+1] * w00 + v01[2*jj+1] * w01 + v10[2*jj+1] * w10 + v11[2*jj+1] * w11;
      __hip_bfloat162 pk = __float22bfloat162_rn(make_float2(e0, e1));
      *(unsigned int*)&s_S[buf][spx * 72 + scs + (jj << 1)] = *(unsigned int*)&pk;
    }
  };

  // prologue: sample tap 0 into buf 0
  sample_issue(0, 0, -1, -1);
  combine_write(0);
  __syncthreads();

  int ng = 0, nkdy = -1, nkdx = 0;   // descriptor state for tap gk+1 (starts at tap 1)
  for (int gk = 0; gk < NGK; ++gk) {
    const int buf = gk & 1;
    // A-fragments for tap gk (issued FIRST so MFMA's wait doesn't drain sample loads)
    short8 af[2][4];
#pragma unroll
    for (int ks = 0; ks < 2; ++ks)
#pragma unroll
      for (int mo = 0; mo < 4; ++mo)
        af[ks][mo] = *(const short8*)(w2u +
            (((gk << 8) + (wv << 6) + (mo << 4) + l15) << 6) + (ks << 5) + (quad << 3));
    // issue sample loads for tap gk+1 (in flight across the MFMAs)
    if (gk + 1 < NGK) {
      sample_issue(gk + 1, ng, nkdy, nkdx);
      if (++nkdx == 2) { nkdx = -1; if (++nkdy == 2) { nkdy = -1; ++ng; } }
    }
    // MFMA tap gk from s_S[buf]
#pragma unroll
    for (int ks = 0; ks < 2; ++ks)
#pragma unroll
      for (int np = 0; np < 2; ++np) {
        short8 bf = *(const short8*)(&s_S[buf][(np * 16 + l15) * 72 + (ks << 5) + (quad << 3)]);
#pragma unroll
        for (int mo = 0; mo < 4; ++mo)
          acc[mo][np] = __builtin_amdgcn_mfma_f32_16x16x32_bf16(af[ks][mo], bf, acc[mo][np], 0, 0, 0);
      }
    if (gk + 1 < NGK) combine_write(buf ^ 1);
    __syncthreads();
  }

  // ---- fused GroupNorm partial stats: group = 8 consecutive o; 32 lanes share a group
#pragma unroll
  for (int mo = 0; mo < 4; ++mo) {
    float s = 0.f, q = 0.f;
#pragma unroll
    for (int np = 0; np < 2; ++np)
#pragma unroll
      for (int r = 0; r < 4; ++r) { float v = acc[mo][np][r]; s += v; q += v * v; }
    for (int m = 1; m < 32; m <<= 1) { s += __shfl_xor(s, m, 64); q += __shfl_xor(q, m, 64); }
    if ((lane & 31) == 0) {
      int gid = ((b * 32) + (wv << 3) + (mo << 1) + (quad >> 1));
      atomicAdd(&st[gid], s);
      atomicAdd(&st[256 + gid], q);
    }
  }

  // ---- epilogue: D layout col(px)=l15, row(o)=quad*4+r
  float* ob = out + (((size_t)b << 8) << 12) + h * WW + px0;
#pragma unroll
  for (int mo = 0; mo < 4; ++mo)
#pragma unroll
    for (int np = 0; np < 2; ++np)
#pragma unroll
      for (int r = 0; r < 4; ++r)
        ob[((size_t)((wv << 6) + (mo << 4) + (quad << 2) + r) << 12) + (np << 4) + l15] =
            acc[mo][np][r];
}

// Normalize + affine + ReLU, finalizing stats from the atomic sums.
__global__ __launch_bounds__(256) void norm_kernel(float* __restrict__ o,
    const float* __restrict__ st, const float* __restrict__ gamma,
    const float* __restrict__ beta) {
  int idx = blockIdx.x * 256 + threadIdx.x;       // over float4s: 2097152 total
  float4* p = (float4*)o;
  int c = (idx >> 10) & 255;
  int b = idx >> 18;
  int g = b * 32 + (c >> 3);
  const float invn = 1.f / 32768.f;
  float mu  = st[g] * invn;
  float var = st[256 + g] * invn - mu * mu;
  float ga = gamma[c] * rsqrtf(var + EPSV);
  float be = beta[c] - mu * ga;
  float4 v = p[idx];
  v.x = fmaxf(fmaf(v.x, ga, be), 0.f);
  v.y = fmaxf(fmaf(v.y, ga, be), 0.f);
  v.z = fmaxf(fmaf(v.z, ga, be), 0.f);
  v.w = fmaxf(fmaf(v.w, ga, be), 0.f);
  p[idx] = v;
}

extern "C" void kernel_launch(void* const* d_in, const int* in_sizes, int n_in,
                              void* d_out, int out_size, void* d_ws, size_t ws_size,
                              hipStream_t stream) {
  const float* x     = (const float*)d_in[0];
  const float* shp   = (const float*)d_in[1];
  const float* woff  = (const float*)d_in[2];
  const float* wdef  = (const float*)d_in[3];
  const float* gamma = (const float*)d_in[4];
  const float* beta  = (const float*)d_in[5];
  float* out = (float*)d_out;
  __hip_bfloat16* w2 = (__hip_bfloat16*)d_ws;                      // 589824 bf16
  float* st = (float*)((char*)d_ws + 589824 * sizeof(__hip_bfloat16)); // 512 floats

  hipLaunchKernelGGL(wt2_kernel,  dim3(2304), dim3(256), 0, stream, wdef, w2, st);
  hipLaunchKernelGGL(conv_kernel, dim3(1024), dim3(256), 0, stream, x, shp, woff, w2, out, st);
  hipLaunchKernelGGL(norm_kernel, dim3(8192), dim3(256), 0, stream, out, st, gamma, beta);
}

// Round 5
// 364.630 us; speedup vs baseline: 1.0148x; 1.0148x over previous
//
#include <hip/hip_runtime.h>
#include <hip/hip_bf16.h>

#define EPSV 1e-5f

typedef __attribute__((ext_vector_type(8))) short short8;
typedef __attribute__((ext_vector_type(4))) float f32x4;

#define LDSU32 __attribute__((address_space(3))) unsigned int
#define GLBU32 const __attribute__((address_space(1))) unsigned int

// ws layout: S (150,994,944 B) | w2 (1,179,648 B) | st (2,048 B)  => ~152.2 MB
#define S_BYTES  150994944ull
#define W2_BYTES 1179648ull

// w_deform (o, g*64+c, kk) fp32 -> w2 bf16 [o][g*576 + k*64 + c]; zero st.
__global__ __launch_bounds__(256) void wt2_kernel(const float* __restrict__ wd,
                                                  __hip_bfloat16* __restrict__ w2,
                                                  float* __restrict__ st) {
  int idx = blockIdx.x * 256 + threadIdx.x;   // 589824 = o*2304 + g*576 + k*64 + c
  int c  = idx & 63;
  int r  = idx >> 6;          // o*36 + g*9 + k
  int k  = r % 9;
  int r2 = r / 9;             // o*4 + g
  int g  = r2 & 3;
  int o  = r2 >> 2;
  w2[idx] = __float2bfloat16(wd[(o * 256 + g * 64 + c) * 9 + k]);
  if (blockIdx.x < 2) st[blockIdx.x * 256 + threadIdx.x] = 0.f;
}

// Barrier-free gather: S^T[b][n=h*64+px][g*576+k*64+c] bf16.
// Block = (b, gk, 8-row tile); 256 thr = 64 px x 4 c-slices(16ch).
__global__ __launch_bounds__(256) void sample_kernel(
    const float* __restrict__ x, const float* __restrict__ shp,
    const float* __restrict__ woff, __hip_bfloat16* __restrict__ S) {
  const int b  = blockIdx.x & 7;              // XCD swizzle: batch -> XCD
  const int r2 = blockIdx.x >> 3;             // 0..287
  const int gk = r2 % 36;
  const int rt = r2 / 36;                     // 0..7
  const int g = gk / 9, k = gk - g * 9;
  const int kdy = k / 3 - 1, kdx = k % 3 - 1;
  const int t  = threadIdx.x;
  const int px = t & 63;
  const int cs = (t >> 6) << 4;

  const float wy0 = woff[gk*8+0], wy1 = woff[gk*8+1], wy2 = woff[gk*8+2], wy3 = woff[gk*8+3];
  const float wx0 = woff[gk*8+4], wx1 = woff[gk*8+5], wx2 = woff[gk*8+6], wx3 = woff[gk*8+7];
  const float* xp = x + ((size_t)(b * 256 + g * 64 + cs) << 12);
  unsigned short* Sb = (unsigned short*)S;

#pragma unroll
  for (int rr = 0; rr < 8; ++rr) {
    const int h = (rt << 3) + rr;
    const float a0 = shp[((b * 4 + 0) * 64 + h) * 64 + px];
    const float a1 = shp[((b * 4 + 1) * 64 + h) * 64 + px];
    const float a2 = shp[((b * 4 + 2) * 64 + h) * 64 + px];
    const float a3 = shp[((b * 4 + 3) * 64 + h) * 64 + px];
    float dy = wy0*a0 + wy1*a1 + wy2*a2 + wy3*a3;
    float dx = wx0*a0 + wx1*a1 + wx2*a2 + wx3*a3;
    float py  = dy + (float)(h + kdy);
    float pxp = dx + (float)(px + kdx);
    float y0f = floorf(py), x0f = floorf(pxp);
    float ly = py - y0f, lx = pxp - x0f;
    int y0 = (int)y0f, x0 = (int)x0f;
    float m_y0 = (y0 >=  0 && y0 <= 63) ? 1.f : 0.f;
    float m_y1 = (y0 >= -1 && y0 <= 62) ? 1.f : 0.f;
    float m_x0 = (x0 >=  0 && x0 <= 63) ? 1.f : 0.f;
    float m_x1 = (x0 >= -1 && x0 <= 62) ? 1.f : 0.f;
    float w00 = (1.f - ly) * (1.f - lx) * m_y0 * m_x0;
    float w01 = (1.f - ly) * lx         * m_y0 * m_x1;
    float w10 = ly         * (1.f - lx) * m_y1 * m_x0;
    float w11 = ly         * lx         * m_y1 * m_x1;
    int yc0 = min(max(y0, 0), 63),     yc1 = min(max(y0 + 1, 0), 63);
    int xc0 = min(max(x0, 0), 63),     xc1 = min(max(x0 + 1, 0), 63);
    int i00 = (yc0 << 6) + xc0, i01 = (yc0 << 6) + xc1;
    int i10 = (yc1 << 6) + xc0, i11 = (yc1 << 6) + xc1;

    unsigned int pk[8];
#pragma unroll
    for (int jj = 0; jj < 8; ++jj) {
      const float* xa = xp + ((size_t)(jj * 2) << 12);
      const float* xb = xa + 4096;
      float e0 = xa[i00]*w00 + xa[i01]*w01 + xa[i10]*w10 + xa[i11]*w11;
      float e1 = xb[i00]*w00 + xb[i01]*w01 + xb[i10]*w10 + xb[i11]*w11;
      __hip_bfloat162 p2 = __float22bfloat162_rn(make_float2(e0, e1));
      pk[jj] = *(unsigned int*)&p2;
    }
    size_t so = (size_t)((b << 12) + (h << 6) + px) * 2304 + g * 576 + k * 64 + cs;
    uint4* dst = (uint4*)(Sb + so);
    dst[0] = make_uint4(pk[0], pk[1], pk[2], pk[3]);
    dst[1] = make_uint4(pk[4], pk[5], pk[6], pk[7]);
  }
}

// m97-style GEMM: out[b][o][n] = sum_K w2[o][K] * S^T[b*4096+n][K], K=2304.
// 128x128 tile, BK=32, global_load_lds(16B), fused GN stats via atomics.
__global__ __launch_bounds__(256) void gemm_kernel(
    const __hip_bfloat16* __restrict__ Sp, const __hip_bfloat16* __restrict__ w2,
    float* __restrict__ out, float* __restrict__ st) {
  __shared__ __align__(16) unsigned short sA[128 * 32];
  __shared__ __align__(16) unsigned short sB[128 * 32];
  const int b  = blockIdx.x & 7;              // XCD swizzle
  const int r2 = blockIdx.x >> 3;             // 0..63
  const int mt = r2 & 1;
  const int nt = r2 >> 1;                     // 0..31
  const int o0 = mt << 7, n0 = nt << 7;
  const int t = threadIdx.x;
  const int wv = t >> 6, lane = t & 63;
  const int quad = lane >> 4, l15 = lane & 15;
  const int wm = wv & 1, wn = wv >> 1;

  const unsigned short* Ab = (const unsigned short*)w2 + (size_t)o0 * 2304;
  const unsigned short* Bb = (const unsigned short*)Sp + (size_t)((b << 12) + n0) * 2304;

  f32x4 acc[4][4];
#pragma unroll
  for (int mo = 0; mo < 4; ++mo)
#pragma unroll
    for (int np = 0; np < 4; ++np) acc[mo][np] = (f32x4){0.f, 0.f, 0.f, 0.f};

  for (int k0 = 0; k0 < 2304; k0 += 32) {
#pragma unroll
    for (int i = 0; i < 2; ++i) {
      const int f = (i << 8) + t;
      const int row = f >> 2, seg = f & 3;
      __builtin_amdgcn_global_load_lds(
          (GLBU32*)(Ab + (size_t)row * 2304 + k0 + (seg << 3)),
          (LDSU32*)(sA + (i << 11) + (wv << 9)), 16, 0, 0);
      __builtin_amdgcn_global_load_lds(
          (GLBU32*)(Bb + (size_t)row * 2304 + k0 + (seg << 3)),
          (LDSU32*)(sB + (i << 11) + (wv << 9)), 16, 0, 0);
    }
    __syncthreads();
    short8 af[4];
#pragma unroll
    for (int mo = 0; mo < 4; ++mo)
      af[mo] = *(const short8*)(sA + (((wm << 6) + (mo << 4) + l15) << 5) + (quad << 3));
#pragma unroll
    for (int np = 0; np < 4; ++np) {
      short8 bf = *(const short8*)(sB + (((wn << 6) + (np << 4) + l15) << 5) + (quad << 3));
#pragma unroll
      for (int mo = 0; mo < 4; ++mo)
        acc[mo][np] = __builtin_amdgcn_mfma_f32_16x16x32_bf16(af[mo], bf, acc[mo][np], 0, 0, 0);
    }
    __syncthreads();
  }

  // Fused GN partial stats: group = 8 consecutive o = quad-pair; gid indep of r.
#pragma unroll
  for (int mo = 0; mo < 4; ++mo) {
    float s = 0.f, q = 0.f;
#pragma unroll
    for (int np = 0; np < 4; ++np)
#pragma unroll
      for (int r = 0; r < 4; ++r) { float v = acc[mo][np][r]; s += v; q += v * v; }
#pragma unroll
    for (int m = 1; m < 16; m <<= 1) { s += __shfl_xor(s, m, 64); q += __shfl_xor(q, m, 64); }
    if (l15 == 0) {
      int gid = (b << 5) + (mt << 4) + (wm << 3) + (mo << 1) + (quad >> 1);
      atomicAdd(&st[gid], s);
      atomicAdd(&st[256 + gid], q);
    }
  }

  // Epilogue: C/D layout col(n)=l15, row(o)=quad*4+r.
  float* ob = out + ((size_t)((b << 8) + o0 + (wm << 6)) << 12) + n0 + (wn << 6);
#pragma unroll
  for (int mo = 0; mo < 4; ++mo)
#pragma unroll
    for (int np = 0; np < 4; ++np)
#pragma unroll
      for (int r = 0; r < 4; ++r)
        ob[((size_t)((mo << 4) + (quad << 2) + r) << 12) + (np << 4) + l15] = acc[mo][np][r];
}

// Normalize + affine + ReLU from atomic sums.
__global__ __launch_bounds__(256) void norm_kernel(float* __restrict__ o,
    const float* __restrict__ st, const float* __restrict__ gamma,
    const float* __restrict__ beta) {
  int idx = blockIdx.x * 256 + threadIdx.x;    // float4s: 2,097,152
  float4* p = (float4*)o;
  int c = (idx >> 10) & 255;
  int b = idx >> 18;
  int g = b * 32 + (c >> 3);
  const float invn = 1.f / 32768.f;
  float mu  = st[g] * invn;
  float var = st[256 + g] * invn - mu * mu;
  float ga = gamma[c] * rsqrtf(var + EPSV);
  float be = beta[c] - mu * ga;
  float4 v = p[idx];
  v.x = fmaxf(fmaf(v.x, ga, be), 0.f);
  v.y = fmaxf(fmaf(v.y, ga, be), 0.f);
  v.z = fmaxf(fmaf(v.z, ga, be), 0.f);
  v.w = fmaxf(fmaf(v.w, ga, be), 0.f);
  p[idx] = v;
}

extern "C" void kernel_launch(void* const* d_in, const int* in_sizes, int n_in,
                              void* d_out, int out_size, void* d_ws, size_t ws_size,
                              hipStream_t stream) {
  const float* x     = (const float*)d_in[0];
  const float* shp   = (const float*)d_in[1];
  const float* woff  = (const float*)d_in[2];
  const float* wdef  = (const float*)d_in[3];
  const float* gamma = (const float*)d_in[4];
  const float* beta  = (const float*)d_in[5];
  float* out = (float*)d_out;
  __hip_bfloat16* S  = (__hip_bfloat16*)d_ws;
  __hip_bfloat16* w2 = (__hip_bfloat16*)((char*)d_ws + S_BYTES);
  float* st          = (float*)((char*)d_ws + S_BYTES + W2_BYTES);

  hipLaunchKernelGGL(wt2_kernel,    dim3(2304), dim3(256), 0, stream, wdef, w2, st);
  hipLaunchKernelGGL(sample_kernel, dim3(2304), dim3(256), 0, stream, x, shp, woff, S);
  hipLaunchKernelGGL(gemm_kernel,   dim3(512),  dim3(256), 0, stream, S, w2, out, st);
  hipLaunchKernelGGL(norm_kernel,   dim3(8192), dim3(256), 0, stream, out, st, gamma, beta);
}